// Round 1
// baseline (878.611 us; speedup 1.0000x reference)
//
#include <hip/hip_runtime.h>
#include <math.h>

#define D 256
#define TOPK 1024
#define EPS 1e-8f

__device__ __forceinline__ unsigned encf(float f){
  unsigned b = __float_as_uint(f);
  return b ^ ((unsigned)((int)b >> 31) | 0x80000000u);
}
__device__ __forceinline__ float decf(unsigned u){
  unsigned b = (u & 0x80000000u) ? (u ^ 0x80000000u) : ~u;
  return __uint_as_float(b);
}

// ---------------------------------------------------------------------------
// K1: precompute U = sym-folded W_e^T W_e, r_e, B[3][256], C[3], rc[3], |q|,
//     zero histograms + scalars.
// Grid: 257 blocks x 256. Blocks 0..255: one row of U. Block 256: extras.
// ---------------------------------------------------------------------------
__global__ __launch_bounds__(256) void k1_setup(
    const float* __restrict__ emb, const float* __restrict__ dtab,
    const float* __restrict__ W, const int* __restrict__ srcp,
    float* __restrict__ U, float* __restrict__ RE, float* __restrict__ Bm,
    float* __restrict__ Cc, float* __restrict__ RC, float* __restrict__ QN,
    unsigned* __restrict__ SC, unsigned* __restrict__ H0)
{
  int tid = threadIdx.x;
  int gid = blockIdx.x*256 + tid;
  if (gid < 6144) H0[gid] = 0u;          // H0,H1,H2 contiguous (2048 each)
  if (gid == 0){
    SC[0]=0u;                 // MAXE (encoded max logit)
    ((float*)SC)[1]=0.0f;     // SUME
    SC[2]=0u;                 // EQC
    SC[3]=0u;                 // PFX
    SC[4]=(unsigned)TOPK;     // KP (remaining quota)
  }
  __shared__ float red[256];
  __shared__ float r67[2];
  if (blockIdx.x < 256){
    int kr = blockIdx.x;      // U row
    int kc = tid;             // U col (coalesced)
    float acc=0.f;
    for (int j=0;j<D;++j)
      acc = fmaf(W[(size_t)j*258 + kr], W[(size_t)j*258 + kc], acc);
    float uv = (kr==kc) ? acc : (kr<kc ? 2.0f*acc : 0.0f);
    U[(size_t)kr*256 + kc] = uv;
  } else {
    int src = srcp[0];
    const float* qv = emb + (size_t)src*D;
    float dt00=dtab[0],dt01=dtab[1],dt10=dtab[2],dt11=dtab[3],dt20=dtab[4],dt21=dtab[5];
    int k = tid;
    float r=0.f,b0=0.f,b1=0.f,b2=0.f;
    for (int j=0;j<D;++j){
      float wk = W[(size_t)j*258 + k];
      float qj = qv[j];
      float w6 = W[(size_t)j*258 + 256];
      float w7 = W[(size_t)j*258 + 257];
      r  = fmaf(qj, wk, r);
      b0 = fmaf(fmaf(w6,dt00, w7*dt01), wk, b0);
      b1 = fmaf(fmaf(w6,dt10, w7*dt11), wk, b1);
      b2 = fmaf(fmaf(w6,dt20, w7*dt21), wk, b2);
    }
    RE[k]=r; Bm[k]=2.f*b0; Bm[256+k]=2.f*b1; Bm[512+k]=2.f*b2;
    float qk = qv[k];
    red[tid]=qk*qk; __syncthreads();
    for (int s2=128;s2>0;s2>>=1){ if (tid<s2) red[tid]+=red[tid+s2]; __syncthreads(); }
    if (tid==0) QN[0] = sqrtf(red[0]);
    if (tid==3 || tid==4){
      int col = 256 + (tid-3);
      float a2=0.f;
      for (int j=0;j<D;++j) a2 = fmaf(qv[j], W[(size_t)j*258+col], a2);
      r67[tid-3]=a2;
    }
    if (tid<3){
      float d0=dtab[2*tid], d1=dtab[2*tid+1];
      float a2=0.f;
      for (int j=0;j<D;++j){
        float v = fmaf(W[(size_t)j*258+256],d0, W[(size_t)j*258+257]*d1);
        a2 = fmaf(v,v,a2);
      }
      Cc[tid]=a2;
    }
    __syncthreads();
    if (tid<3){
      float d0=dtab[2*tid], d1=dtab[2*tid+1];
      RC[tid] = r67[0]*d0 + r67[1]*d1;
    }
  }
}

// ---------------------------------------------------------------------------
// K2: per-row quadratic form Q = x^T U x (upper-tri tiles) + s = x.r
//     -> logits s, weighted-cos key u. Thread = row. U rows via s_load (uniform).
// ---------------------------------------------------------------------------
__global__ __launch_bounds__(256) void k2_main(
    const float* __restrict__ emb, const int* __restrict__ dist,
    const float* __restrict__ U, const float* __restrict__ RE,
    const float* __restrict__ Bm, const float* __restrict__ Cc,
    const float* __restrict__ RC, const float* __restrict__ QN,
    float* __restrict__ Sv, unsigned* __restrict__ UK,
    unsigned* __restrict__ SC, int N)
{
  int tid = threadIdx.x;
  int n = blockIdx.x*256 + tid;
  bool ok = n < N;
  int dv = ok ? dist[n] : 3;
  int didx = dv-1; didx = didx<0?0:(didx>2?2:didx);
  const float* xrow = emb + (size_t)(ok?n:0)*D;
  const float* Bv = Bm + didx*256;
  float xa[32], xb[32];
  float qacc=0.f, sacc=0.f;
  for (int a=0;a<8;++a){
    const float4* pa = (const float4*)(xrow + a*32);
    #pragma unroll
    for (int i=0;i<8;++i){
      float4 v = pa[i];
      xa[4*i+0]=v.x; xa[4*i+1]=v.y; xa[4*i+2]=v.z; xa[4*i+3]=v.w;
    }
    #pragma unroll
    for (int i=0;i<32;++i){
      sacc = fmaf(xa[i], RE[a*32+i], sacc);   // uniform -> s_load
      qacc = fmaf(xa[i], Bv[a*32+i], qacc);   // per-lane (3 variants), L1-hot
    }
    for (int b=a;b<8;++b){
      const float4* pb = (const float4*)(xrow + b*32);
      #pragma unroll
      for (int i=0;i<8;++i){
        float4 v = pb[i];
        xb[4*i+0]=v.x; xb[4*i+1]=v.y; xb[4*i+2]=v.z; xb[4*i+3]=v.w;
      }
      const float* Ut = U + (size_t)(a*32)*256 + b*32;
      #pragma unroll
      for (int i=0;i<32;++i){
        const float* Ur = Ut + (size_t)i*256;  // wave-uniform address
        float t0=0.f,t1=0.f,t2=0.f,t3=0.f;
        #pragma unroll
        for (int j=0;j<8;++j){
          t0 = fmaf(Ur[4*j+0], xb[4*j+0], t0);
          t1 = fmaf(Ur[4*j+1], xb[4*j+1], t1);
          t2 = fmaf(Ur[4*j+2], xb[4*j+2], t2);
          t3 = fmaf(Ur[4*j+3], xb[4*j+3], t3);
        }
        qacc = fmaf(xa[i], (t0+t1)+(t2+t3), qacc);
      }
    }
  }
  float Q = qacc + Cc[didx];
  float s = sacc + RC[didx];
  float qn = QN[0];
  float denom = fmaxf(sqrtf(Q), EPS) * fmaxf(qn, EPS);
  float cosv = s/denom;
  float wgt = (dv==1)?1.5f : ((dv==2)?2.0f:1.0f);
  float wv = (dv<=2) ? cosv*wgt : -INFINITY;
  if (ok){ Sv[n]=s; UK[n]=encf(wv); }
  __shared__ float red[256];
  red[tid] = ok ? s : -INFINITY;
  __syncthreads();
  for (int st=128;st>0;st>>=1){ if (tid<st) red[tid]=fmaxf(red[tid],red[tid+st]); __syncthreads(); }
  if (tid==0) atomicMax(&SC[0], encf(red[0]));
}

// ---------------------------------------------------------------------------
// Radix-select histogram pass (LDS-privatized). pass0: bits[31:21] (excl -inf),
// pass1: bits[20:10], pass2: bits[9:0].
// ---------------------------------------------------------------------------
__global__ __launch_bounds__(256) void kh_hist(
    const unsigned* __restrict__ UK, const unsigned* __restrict__ SC,
    unsigned* __restrict__ Hp, int pass, int N)
{
  __shared__ unsigned h[2048];
  int bins = (pass==2)?1024:2048;
  int tid = threadIdx.x;
  for (int i=tid;i<bins;i+=256) h[i]=0u;
  __syncthreads();
  unsigned pfx = SC[3];
  int n = blockIdx.x*256 + tid;
  if (n < N){
    unsigned u = UK[n];
    bool incl; unsigned bin;
    if (pass==0){ incl = (u > 0x007FFFFFu); bin = u>>21; }        // drop -inf flood
    else if (pass==1){ incl = ((u>>21)==pfx); bin = (u>>10)&2047u; }
    else { incl = ((u>>10)==pfx); bin = u & 1023u; }
    if (incl) atomicAdd(&h[bin], 1u);
  }
  __syncthreads();
  for (int i=tid;i<bins;i+=256){ unsigned v=h[i]; if (v) atomicAdd(&Hp[i], v); }
}

__global__ __launch_bounds__(256) void ks_scan(
    const unsigned* __restrict__ Hp, unsigned* __restrict__ SC, int pass)
{
  __shared__ unsigned h[2048];
  __shared__ unsigned part[256];
  int bins=(pass==2)?1024:2048;
  int per = bins/256;
  int tid=threadIdx.x;
  unsigned ps=0;
  for (int i=0;i<per;++i){ unsigned v=Hp[tid*per+i]; h[tid*per+i]=v; ps+=v; }
  part[tid]=ps;
  __syncthreads();
  if (tid==0){
    unsigned Kp = SC[4];
    unsigned cum=0;
    int sc2=0;
    for (int t=255;t>=0;--t){
      if (cum + part[t] >= Kp){ sc2=t; break; }
      cum += part[t];
    }
    int sel = sc2*per;
    for (int b2=sc2*per+per-1; b2>=sc2*per; --b2){
      if (cum + h[b2] >= Kp){ sel=b2; break; }
      cum += h[b2];
    }
    SC[4] = Kp - cum;                         // remaining quota among == bin
    int bitsp = (pass==2)?10:11;
    SC[3] = (SC[3] << bitsp) | (unsigned)sel; // extend prefix
  }
}

// ---------------------------------------------------------------------------
// K6: write mask (topk-strict | dist==1 | src), collect ==T list, sum-exp.
// ---------------------------------------------------------------------------
__global__ __launch_bounds__(256) void k6_final(
    const int* __restrict__ dist, const int* __restrict__ srcp,
    const float* __restrict__ Sv, const unsigned* __restrict__ UK,
    unsigned* __restrict__ SC, unsigned* __restrict__ EQL,
    float* __restrict__ out, int N)
{
  int tid=threadIdx.x;
  int n=blockIdx.x*256+tid;
  unsigned T = SC[3];
  float M = decf(SC[0]);
  int src = srcp[0];
  float e=0.f;
  if (n<N){
    unsigned u = UK[n];
    int dv = dist[n];
    bool base = (u>T) || (dv==1) || (n==src);
    out[1+n] = base ? 1.0f : 0.0f;
    if (u==T){
      unsigned i = atomicAdd(&SC[2], 1u);
      if (i < 4096u) EQL[i] = (unsigned)n;
    }
    e = expf(Sv[n]-M);
  }
  __shared__ float red[256];
  red[tid]=e; __syncthreads();
  for (int st=128;st>0;st>>=1){ if (tid<st) red[tid]+=red[tid+st]; __syncthreads(); }
  if (tid==0) atomicAdd((float*)&SC[1], red[0]);
}

// ---------------------------------------------------------------------------
// K7: loss = L*lse - sum(logits[labels]); resolve ==T ties lowest-index-first.
// ---------------------------------------------------------------------------
__global__ __launch_bounds__(256) void k7_loss(
    const int* __restrict__ labels, const float* __restrict__ Sv,
    unsigned* __restrict__ SC, const unsigned* __restrict__ EQL,
    float* __restrict__ out, int L)
{
  __shared__ float red[256];
  __shared__ unsigned lst[4096];
  int tid=threadIdx.x;
  float v=0.f;
  if (tid<L) v = Sv[labels[tid]];
  red[tid]=v; __syncthreads();
  for (int st=128;st>0;st>>=1){ if (tid<st) red[tid]+=red[tid+st]; __syncthreads(); }
  if (tid==0){
    float M = decf(SC[0]);
    float se = ((const float*)SC)[1];
    out[0] = (float)L*(M + logf(se)) - red[0];
  }
  unsigned cnt = SC[2]; if (cnt>4096u) cnt=4096u;
  unsigned quota = SC[4];
  for (unsigned i=tid;i<cnt;i+=256u) lst[i]=EQL[i];
  __syncthreads();
  if (cnt <= quota){
    for (unsigned i=tid;i<cnt;i+=256u) out[1+lst[i]] = 1.0f;
  } else {
    for (unsigned i=tid;i<cnt;i+=256u){
      unsigned me=lst[i]; unsigned rank=0;
      for (unsigned j=0;j<cnt;++j) rank += (lst[j]<me)?1u:0u;
      if (rank<quota) out[1+me]=1.0f;   // stable tie-break: lowest index wins
    }
  }
}

extern "C" void kernel_launch(void* const* d_in, const int* in_sizes, int n_in,
                              void* d_out, int out_size, void* d_ws, size_t ws_size,
                              hipStream_t stream)
{
  const float* emb  = (const float*)d_in[0];
  const float* dtab = (const float*)d_in[1];
  const float* W    = (const float*)d_in[2];
  const int* dist   = (const int*)d_in[3];
  const int* labels = (const int*)d_in[4];
  const int* srcp   = (const int*)d_in[5];
  float* out = (float*)d_out;
  int N = in_sizes[3];
  int L = in_sizes[4];

  float* ws = (float*)d_ws;
  float* U  = ws;                       // 65536
  float* RE = U + 65536;                // 256
  float* Bm = RE + 256;                 // 768
  float* Cc = Bm + 768;                 // 3
  float* RC = Cc + 3;                   // 3
  float* QN = RC + 3;                   // 1
  unsigned* SC = (unsigned*)(QN + 1);   // 8 scalars
  unsigned* H0 = SC + 8;                // 2048
  unsigned* H1 = H0 + 2048;             // 2048
  unsigned* H2 = H1 + 2048;             // 2048 (1024 used)
  float* Sv = (float*)(H2 + 2048);      // N
  unsigned* UK = (unsigned*)(Sv + N);   // N
  unsigned* EQL = UK + N;               // 4096
  // total ~1.9 MB of ws

  int grid = (N + 255)/256;
  k1_setup<<<257,256,0,stream>>>(emb, dtab, W, srcp, U, RE, Bm, Cc, RC, QN, SC, H0);
  k2_main<<<grid,256,0,stream>>>(emb, dist, U, RE, Bm, Cc, RC, QN, Sv, UK, SC, N);
  kh_hist<<<grid,256,0,stream>>>(UK, SC, H0, 0, N);
  ks_scan<<<1,256,0,stream>>>(H0, SC, 0);
  kh_hist<<<grid,256,0,stream>>>(UK, SC, H1, 1, N);
  ks_scan<<<1,256,0,stream>>>(H1, SC, 1);
  kh_hist<<<grid,256,0,stream>>>(UK, SC, H2, 2, N);
  ks_scan<<<1,256,0,stream>>>(H2, SC, 2);
  k6_final<<<grid,256,0,stream>>>(dist, srcp, Sv, UK, SC, EQL, out, N);
  k7_loss<<<1,256,0,stream>>>(labels, Sv, SC, EQL, out, L);
}

// Round 4
// 758.416 us; speedup vs baseline: 1.1585x; 1.1585x over previous
//
#include <hip/hip_runtime.h>
#include <math.h>

#define D 256
#define TOPK 1024
#define EPS 1e-8f

__device__ __forceinline__ unsigned encf(float f){
  unsigned b = __float_as_uint(f);
  return b ^ ((unsigned)((int)b >> 31) | 0x80000000u);
}
__device__ __forceinline__ float decf(unsigned u){
  unsigned b = (u & 0x80000000u) ? (u ^ 0x80000000u) : ~u;
  return __uint_as_float(b);
}

// Upper-triangle 8x8 chunk tiles (a<=b), packed a*8+b, 9 per wave.
static __device__ const unsigned char TLIST[36] = {
  0x00,0x01,0x02,0x03,0x04,0x05,0x06,0x07, 0x09,        // w0: (0,0..7),(1,1)
  0x0A,0x0B,0x0C,0x0D,0x0E,0x0F, 0x12,0x13,0x14,        // w1: (1,2..7),(2,2..4)
  0x15,0x16,0x17, 0x1B,0x1C,0x1D,0x1E,0x1F, 0x24,       // w2: (2,5..7),(3,3..7),(4,4)
  0x25,0x26,0x27, 0x2D,0x2E,0x2F, 0x36,0x37, 0x3F       // w3: (4,5..7),(5,5..7),(6,6..7),(7,7)
};

// ---------------------------------------------------------------------------
// K1: precompute U = sym-folded W_e^T W_e, r_e, B[3][256], C[3], rc[3], |q|,
//     zero histograms + scalars.
// ---------------------------------------------------------------------------
__global__ __launch_bounds__(256) void k1_setup(
    const float* __restrict__ emb, const float* __restrict__ dtab,
    const float* __restrict__ W, const int* __restrict__ srcp,
    float* __restrict__ U, float* __restrict__ RE, float* __restrict__ Bm,
    float* __restrict__ Cc, float* __restrict__ RC, float* __restrict__ QN,
    unsigned* __restrict__ SC, unsigned* __restrict__ H0)
{
  int tid = threadIdx.x;
  int gid = blockIdx.x*256 + tid;
  if (gid < 6144) H0[gid] = 0u;          // H0,H1,H2 contiguous (2048 each)
  if (gid == 0){
    SC[0]=0u;                 // MAXE (encoded max logit)
    ((float*)SC)[1]=0.0f;     // SUME
    SC[2]=0u;                 // EQC
    SC[3]=0u;                 // PFX
    SC[4]=(unsigned)TOPK;     // KP (remaining quota)
  }
  __shared__ float red[256];
  __shared__ float r67[2];
  if (blockIdx.x < 256){
    int kr = blockIdx.x;      // U row
    int kc = tid;             // U col (coalesced)
    float acc=0.f;
    for (int j=0;j<D;++j)
      acc = fmaf(W[(size_t)j*258 + kr], W[(size_t)j*258 + kc], acc);
    float uv = (kr==kc) ? acc : (kr<kc ? 2.0f*acc : 0.0f);
    U[(size_t)kr*256 + kc] = uv;
  } else {
    int src = srcp[0];
    const float* qv = emb + (size_t)src*D;
    float dt00=dtab[0],dt01=dtab[1],dt10=dtab[2],dt11=dtab[3],dt20=dtab[4],dt21=dtab[5];
    int k = tid;
    float r=0.f,b0=0.f,b1=0.f,b2=0.f;
    for (int j=0;j<D;++j){
      float wk = W[(size_t)j*258 + k];
      float qj = qv[j];
      float w6 = W[(size_t)j*258 + 256];
      float w7 = W[(size_t)j*258 + 257];
      r  = fmaf(qj, wk, r);
      b0 = fmaf(fmaf(w6,dt00, w7*dt01), wk, b0);
      b1 = fmaf(fmaf(w6,dt10, w7*dt11), wk, b1);
      b2 = fmaf(fmaf(w6,dt20, w7*dt21), wk, b2);
    }
    RE[k]=r; Bm[k]=2.f*b0; Bm[256+k]=2.f*b1; Bm[512+k]=2.f*b2;
    float qk = qv[k];
    red[tid]=qk*qk; __syncthreads();
    for (int s2=128;s2>0;s2>>=1){ if (tid<s2) red[tid]+=red[tid+s2]; __syncthreads(); }
    if (tid==0) QN[0] = sqrtf(red[0]);
    if (tid==3 || tid==4){
      int col = 256 + (tid-3);
      float a2=0.f;
      for (int j=0;j<D;++j) a2 = fmaf(qv[j], W[(size_t)j*258+col], a2);
      r67[tid-3]=a2;
    }
    if (tid<3){
      float d0=dtab[2*tid], d1=dtab[2*tid+1];
      float a2=0.f;
      for (int j=0;j<D;++j){
        float v = fmaf(W[(size_t)j*258+256],d0, W[(size_t)j*258+257]*d1);
        a2 = fmaf(v,v,a2);
      }
      Cc[tid]=a2;
    }
    __syncthreads();
    if (tid<3){
      float d0=dtab[2*tid], d1=dtab[2*tid+1];
      RC[tid] = r67[0]*d0 + r67[1]*d1;
    }
  }
}

// ---------------------------------------------------------------------------
// K2: per-row quadratic form Q = x^T U x, 36 upper-tri tiles split 9/9/9/9
// across the block's 4 waves via TLIST (wave-uniform -> U rows stay s_load).
// Wave 0 additionally does the r-dot/B-dot and the epilogue + fused pass-0
// histogram. Compact: single tile-body instantiation, runtime loop (keeps
// compile time sane vs full 36-tile unroll).
// ---------------------------------------------------------------------------
#define LOADC(dst, c) do { const float4* _p=(const float4*)(xrow+(c)*32); \
  _Pragma("unroll") for(int _i=0;_i<8;++_i){ float4 _v=_p[_i]; \
  dst[4*_i]=_v.x; dst[4*_i+1]=_v.y; dst[4*_i+2]=_v.z; dst[4*_i+3]=_v.w; } } while(0)

__global__ __launch_bounds__(256) void k2_main(
    const float* __restrict__ emb, const int* __restrict__ dist,
    const float* __restrict__ U, const float* __restrict__ RE,
    const float* __restrict__ Bm, const float* __restrict__ Cc,
    const float* __restrict__ RC, const float* __restrict__ QN,
    float* __restrict__ Sv, unsigned* __restrict__ UK,
    unsigned* __restrict__ SC, unsigned* __restrict__ H0, int N)
{
  int tid = threadIdx.x;
  int wave = tid >> 6;
  int lane = tid & 63;
  int row = blockIdx.x*64 + lane;
  bool ok = row < N;
  const float* xrow = emb + (size_t)(ok?row:0)*D;
  float xa[32], xb[32];
  float qacc=0.f, sacc=0.f;
  int dv = 3, didx = 2;

  __shared__ float qred[256];
  __shared__ unsigned h[2048];
  for (int i=tid;i<2048;i+=256) h[i]=0u;

  if (wave==0){
    dv = ok ? dist[row] : 3;
    didx = dv-1; didx = didx<0?0:(didx>2?2:didx);
    const float* Bv = Bm + didx*256;
    for (int c=0;c<8;++c){
      LOADC(xb,c);
      #pragma unroll
      for (int i=0;i<32;++i){
        sacc = fmaf(xb[i], RE[c*32+i], sacc);
        qacc = fmaf(xb[i], Bv[c*32+i], qacc);
      }
    }
  }

  int aprev = -1;
  for (int t=0;t<9;++t){
    int ab = (int)TLIST[__builtin_amdgcn_readfirstlane(wave*9 + t)];
    int a = ab >> 3, b = ab & 7;
    if (a != aprev){ LOADC(xa,a); aprev = a; }
    LOADC(xb,b);
    const float* Ut = U + (size_t)(a*32)*256 + b*32;
    #pragma unroll
    for (int i=0;i<32;++i){
      const float* Ur = Ut + (size_t)i*256;   // scalar address -> s_load
      float t0=0.f,t1=0.f,t2=0.f,t3=0.f;
      #pragma unroll
      for (int j=0;j<8;++j){
        t0 = fmaf(Ur[4*j+0], xb[4*j+0], t0);
        t1 = fmaf(Ur[4*j+1], xb[4*j+1], t1);
        t2 = fmaf(Ur[4*j+2], xb[4*j+2], t2);
        t3 = fmaf(Ur[4*j+3], xb[4*j+3], t3);
      }
      qacc = fmaf(xa[i], (t0+t1)+(t2+t3), qacc);
    }
  }

  qred[tid] = qacc;
  __syncthreads();

  if (wave==0){
    float qtot = qacc + qred[64+lane] + qred[128+lane] + qred[192+lane];
    float Q = qtot + Cc[didx];
    float s = sacc + RC[didx];
    float qn = QN[0];
    float denom = fmaxf(sqrtf(Q), EPS) * fmaxf(qn, EPS);
    float cosv = s/denom;
    float wgt = (dv==1)?1.5f : ((dv==2)?2.0f:1.0f);
    float wv = (dv<=2) ? cosv*wgt : -INFINITY;
    unsigned u = encf(wv);
    if (ok){ Sv[row]=s; UK[row]=u; if (u > 0x007FFFFFu) atomicAdd(&h[u>>21],1u); }
    float m = ok ? s : -INFINITY;
    #pragma unroll
    for (int off=32;off>0;off>>=1) m = fmaxf(m, __shfl_down(m, off));
    if (lane==0) atomicMax(&SC[0], encf(m));
  }
  __syncthreads();
  for (int i=tid;i<2048;i+=256){ unsigned v=h[i]; if (v) atomicAdd(&H0[i], v); }
}

// ---------------------------------------------------------------------------
// Radix-select histogram passes 1,2 (LDS-privatized).
// pass1: bits[20:10] given prefix bits[31:21]; pass2: bits[9:0].
// ---------------------------------------------------------------------------
__global__ __launch_bounds__(256) void kh_hist(
    const unsigned* __restrict__ UK, const unsigned* __restrict__ SC,
    unsigned* __restrict__ Hp, int pass, int N)
{
  __shared__ unsigned h[2048];
  int bins = (pass==2)?1024:2048;
  int tid = threadIdx.x;
  for (int i=tid;i<bins;i+=256) h[i]=0u;
  __syncthreads();
  unsigned pfx = SC[3];
  int n = blockIdx.x*256 + tid;
  if (n < N){
    unsigned u = UK[n];
    bool incl; unsigned bin;
    if (pass==1){ incl = ((u>>21)==pfx); bin = (u>>10)&2047u; }
    else { incl = ((u>>10)==pfx); bin = u & 1023u; }
    if (incl) atomicAdd(&h[bin], 1u);
  }
  __syncthreads();
  for (int i=tid;i<bins;i+=256){ unsigned v=h[i]; if (v) atomicAdd(&Hp[i], v); }
}

__global__ __launch_bounds__(256) void ks_scan(
    const unsigned* __restrict__ Hp, unsigned* __restrict__ SC, int pass)
{
  __shared__ unsigned h[2048];
  __shared__ unsigned part[256];
  int bins=(pass==2)?1024:2048;
  int per = bins/256;
  int tid=threadIdx.x;
  unsigned ps=0;
  for (int i=0;i<per;++i){ unsigned v=Hp[tid*per+i]; h[tid*per+i]=v; ps+=v; }
  part[tid]=ps;
  __syncthreads();
  if (tid==0){
    unsigned Kp = SC[4];
    unsigned cum=0;
    int sc2=0;
    for (int t=255;t>=0;--t){
      if (cum + part[t] >= Kp){ sc2=t; break; }
      cum += part[t];
    }
    int sel = sc2*per;
    for (int b2=sc2*per+per-1; b2>=sc2*per; --b2){
      if (cum + h[b2] >= Kp){ sel=b2; break; }
      cum += h[b2];
    }
    SC[4] = Kp - cum;                         // remaining quota among == bin
    int bitsp = (pass==2)?10:11;
    SC[3] = (SC[3] << bitsp) | (unsigned)sel; // extend prefix
  }
}

// ---------------------------------------------------------------------------
// K6: write mask (topk-strict | dist==1 | src), collect ==T list, sum-exp.
// ---------------------------------------------------------------------------
__global__ __launch_bounds__(256) void k6_final(
    const int* __restrict__ dist, const int* __restrict__ srcp,
    const float* __restrict__ Sv, const unsigned* __restrict__ UK,
    unsigned* __restrict__ SC, unsigned* __restrict__ EQL,
    float* __restrict__ out, int N)
{
  int tid=threadIdx.x;
  int n=blockIdx.x*256+tid;
  unsigned T = SC[3];
  float M = decf(SC[0]);
  int src = srcp[0];
  float e=0.f;
  if (n<N){
    unsigned u = UK[n];
    int dv = dist[n];
    bool base = (u>T) || (dv==1) || (n==src);
    out[1+n] = base ? 1.0f : 0.0f;
    if (u==T){
      unsigned i = atomicAdd(&SC[2], 1u);
      if (i < 4096u) EQL[i] = (unsigned)n;
    }
    e = expf(Sv[n]-M);
  }
  __shared__ float red[256];
  red[tid]=e; __syncthreads();
  for (int st=128;st>0;st>>=1){ if (tid<st) red[tid]+=red[tid+st]; __syncthreads(); }
  if (tid==0) atomicAdd((float*)&SC[1], red[0]);
}

// ---------------------------------------------------------------------------
// K7: loss = L*lse - sum(logits[labels]); resolve ==T ties lowest-index-first.
// ---------------------------------------------------------------------------
__global__ __launch_bounds__(256) void k7_loss(
    const int* __restrict__ labels, const float* __restrict__ Sv,
    unsigned* __restrict__ SC, const unsigned* __restrict__ EQL,
    float* __restrict__ out, int L)
{
  __shared__ float red[256];
  __shared__ unsigned lst[4096];
  int tid=threadIdx.x;
  float v=0.f;
  if (tid<L) v = Sv[labels[tid]];
  red[tid]=v; __syncthreads();
  for (int st=128;st>0;st>>=1){ if (tid<st) red[tid]+=red[tid+st]; __syncthreads(); }
  if (tid==0){
    float M = decf(SC[0]);
    float se = ((const float*)SC)[1];
    out[0] = (float)L*(M + logf(se)) - red[0];
  }
  unsigned cnt = SC[2]; if (cnt>4096u) cnt=4096u;
  unsigned quota = SC[4];
  for (unsigned i=tid;i<cnt;i+=256u) lst[i]=EQL[i];
  __syncthreads();
  if (cnt <= quota){
    for (unsigned i=tid;i<cnt;i+=256u) out[1+lst[i]] = 1.0f;
  } else {
    for (unsigned i=tid;i<cnt;i+=256u){
      unsigned me=lst[i]; unsigned rank=0;
      for (unsigned j=0;j<cnt;++j) rank += (lst[j]<me)?1u:0u;
      if (rank<quota) out[1+me]=1.0f;   // stable tie-break: lowest index wins
    }
  }
}

extern "C" void kernel_launch(void* const* d_in, const int* in_sizes, int n_in,
                              void* d_out, int out_size, void* d_ws, size_t ws_size,
                              hipStream_t stream)
{
  const float* emb  = (const float*)d_in[0];
  const float* dtab = (const float*)d_in[1];
  const float* W    = (const float*)d_in[2];
  const int* dist   = (const int*)d_in[3];
  const int* labels = (const int*)d_in[4];
  const int* srcp   = (const int*)d_in[5];
  float* out = (float*)d_out;
  int N = in_sizes[3];
  int L = in_sizes[4];

  float* ws = (float*)d_ws;
  float* U  = ws;                       // 65536
  float* RE = U + 65536;                // 256
  float* Bm = RE + 256;                 // 768
  float* Cc = Bm + 768;                 // 3
  float* RC = Cc + 3;                   // 3
  float* QN = RC + 3;                   // 1
  unsigned* SC = (unsigned*)(QN + 1);   // 8 scalars
  unsigned* H0 = SC + 8;                // 2048
  unsigned* H1 = H0 + 2048;             // 2048
  unsigned* H2 = H1 + 2048;             // 2048 (1024 used)
  float* Sv = (float*)(H2 + 2048);      // N
  unsigned* UK = (unsigned*)(Sv + N);   // N
  unsigned* EQL = UK + N;               // 4096

  int grid  = (N + 255)/256;
  int grid2 = (N + 63)/64;
  k1_setup<<<257,256,0,stream>>>(emb, dtab, W, srcp, U, RE, Bm, Cc, RC, QN, SC, H0);
  k2_main<<<grid2,256,0,stream>>>(emb, dist, U, RE, Bm, Cc, RC, QN, Sv, UK, SC, H0, N);
  ks_scan<<<1,256,0,stream>>>(H0, SC, 0);
  kh_hist<<<grid,256,0,stream>>>(UK, SC, H1, 1, N);
  ks_scan<<<1,256,0,stream>>>(H1, SC, 1);
  kh_hist<<<grid,256,0,stream>>>(UK, SC, H2, 2, N);
  ks_scan<<<1,256,0,stream>>>(H2, SC, 2);
  k6_final<<<grid,256,0,stream>>>(dist, srcp, Sv, UK, SC, EQL, out, N);
  k7_loss<<<1,256,0,stream>>>(labels, Sv, SC, EQL, out, L);
}